// Round 1
// baseline (2078.424 us; speedup 1.0000x reference)
//
#include <hip/hip_runtime.h>
#include <hip/hip_bf16.h>
#include <cstdint>
#include <cstddef>

// GCNClassifier on MI355X.
// Pipeline per call (all on `stream`, graph-capture safe):
//  1. CSR build: degree (atomics) -> exclusive scan -> bucket fill.
//  2. dis = rsqrt(deg+1); edge weight computed on the fly as dis[src]*dis[dst].
//  3. x -> bf16; W1..W4 -> transposed bf16 (Wt[n][k]).
//  4. Per layer: bf16 MFMA GEMM (128x128 tile, global_load_lds staging) -> per-dst
//     gather-aggregate (1 wave/node, 1KB coalesced row gathers from L3-resident xw).
//  5. mean-pool (block partials + 256-address atomics) -> FC head -> sigmoid.
// Workspace need ~318 MB (3x N*512 bf16 ping-pong buffers + CSR).

typedef unsigned short u16;
typedef unsigned int u32;
typedef __bf16 bf16x8 __attribute__((ext_vector_type(8)));
typedef float f32x4 __attribute__((ext_vector_type(4)));

__device__ __forceinline__ u16 f2bf(float f) {
  u32 u = __builtin_bit_cast(u32, f);
  u += 0x7fffu + ((u >> 16) & 1u);   // round-to-nearest-even
  return (u16)(u >> 16);
}
__device__ __forceinline__ float bf2f(u16 h) {
  return __builtin_bit_cast(float, (u32)h << 16);
}
__device__ __forceinline__ void g2lds16(const void* g, void* l) {
  // async global->LDS, 16B/lane; LDS dst = wave-uniform base + lane*16
  __builtin_amdgcn_global_load_lds((__attribute__((address_space(1))) void*)g,
                                   (__attribute__((address_space(3))) void*)l, 16, 0, 0);
}

// ---------------------------------------------------------------- init / CSR
__global__ __launch_bounds__(256) void init_kernel(int* __restrict__ deg,
                                                   int* __restrict__ cursor,
                                                   float* __restrict__ pool, int N) {
  int i = blockIdx.x * 256 + threadIdx.x;
  if (i < N) { deg[i] = 0; cursor[i] = 0; }
  if (i < 256) pool[i] = 0.f;
}

// Detect int64 vs int32 storage of edge_index: sample 256 odd 4B words from the
// front (int64 high words are always 0 since values < 1e5; int32 src values are
// random in [0,1e5) so all-zero is impossible in practice).
__global__ void detect_kernel(const int* __restrict__ ei, int* __restrict__ flag) {
  __shared__ int nz;
  if (threadIdx.x == 0) nz = 0;
  __syncthreads();
  if (ei[2 * threadIdx.x + 1] != 0) atomicAdd(&nz, 1);
  __syncthreads();
  if (threadIdx.x == 0) *flag = (nz == 0) ? 1 : 0;
}

__device__ __forceinline__ int ld_src(const int* ei, int E, int e, int f64) {
  return f64 ? (int)((const long long*)ei)[e] : ei[e];
}
__device__ __forceinline__ int ld_dst(const int* ei, int E, int e, int f64) {
  return f64 ? (int)((const long long*)ei)[(long long)E + e] : ei[E + e];
}

__global__ __launch_bounds__(256) void degree_kernel(const int* __restrict__ ei,
                                                     const int* __restrict__ flag,
                                                     int* __restrict__ deg, int E) {
  int e = blockIdx.x * 256 + threadIdx.x;
  if (e >= E) return;
  int f = *flag;
  atomicAdd(&deg[ld_dst(ei, E, e, f)], 1);
}

__global__ __launch_bounds__(256) void dis_kernel(const int* __restrict__ deg,
                                                  float* __restrict__ dis, int N) {
  int i = blockIdx.x * 256 + threadIdx.x;
  if (i < N) dis[i] = rsqrtf((float)deg[i] + 1.0f);
}

__global__ __launch_bounds__(1024) void scan1_kernel(const int* __restrict__ deg,
                                                     int* __restrict__ rs,
                                                     int* __restrict__ bsum, int N) {
  __shared__ int s[1024];
  int tid = threadIdx.x;
  int i = blockIdx.x * 1024 + tid;
  int v = (i < N) ? deg[i] : 0;
  s[tid] = v;
  __syncthreads();
  for (int off = 1; off < 1024; off <<= 1) {
    int t = (tid >= off) ? s[tid - off] : 0;
    __syncthreads();
    s[tid] += t;
    __syncthreads();
  }
  if (i < N) rs[i] = s[tid] - v;        // exclusive
  if (tid == 1023) bsum[blockIdx.x] = s[1023];
}

__global__ void scan2_kernel(const int* __restrict__ bsum, int* __restrict__ boff, int nb) {
  if (threadIdx.x == 0) {
    int run = 0;
    for (int b = 0; b < nb; ++b) { boff[b] = run; run += bsum[b]; }
  }
}

__global__ __launch_bounds__(256) void scan3_kernel(int* __restrict__ rs,
                                                    const int* __restrict__ boff, int N) {
  int i = blockIdx.x * 256 + threadIdx.x;
  if (i < N) rs[i] += boff[i >> 10];
}

__global__ __launch_bounds__(256) void fill_kernel(const int* __restrict__ ei,
                                                   const int* __restrict__ flag,
                                                   const int* __restrict__ rs,
                                                   int* __restrict__ cursor,
                                                   int* __restrict__ colv, int E) {
  int e = blockIdx.x * 256 + threadIdx.x;
  if (e >= E) return;
  int f = *flag;
  int s = ld_src(ei, E, e, f);
  int d = ld_dst(ei, E, e, f);
  int p = atomicAdd(&cursor[d], 1);
  colv[rs[d] + p] = s;
}

// ---------------------------------------------------------------- converts
__global__ __launch_bounds__(256) void convx_kernel(const float* __restrict__ x,
                                                    u16* __restrict__ xb, size_t n) {
  size_t i = ((size_t)blockIdx.x * 256 + threadIdx.x) * 4;
  if (i >= n) return;
  float4 v = *reinterpret_cast<const float4*>(x + i);
  typedef u16 u16x4 __attribute__((ext_vector_type(4)));
  u16x4 o;
  o[0] = f2bf(v.x); o[1] = f2bf(v.y); o[2] = f2bf(v.z); o[3] = f2bf(v.w);
  *reinterpret_cast<u16x4*>(xb + i) = o;
}

// W[k][n] fp32 -> Wt[n][k] bf16 (K fixed 512)
__global__ __launch_bounds__(256) void convw_kernel(const float* __restrict__ W,
                                                    u16* __restrict__ Wt, int Nout) {
  int id = blockIdx.x * 256 + threadIdx.x;
  if (id >= 512 * Nout) return;
  int k = id / Nout, n = id - k * Nout;
  Wt[n * 512 + k] = f2bf(W[id]);
}

// ---------------------------------------------------------------- GEMM
// C[M][Nout] = A[M][512] @ W, with Wt[n][k]. 128x128 tile, BK=32, 4 waves 2x2,
// each wave 4x4 tiles of mfma_f32_16x16x32_bf16.
__global__ __launch_bounds__(256, 2)
void gemm_kernel(const u16* __restrict__ A, const u16* __restrict__ Bt,
                 u16* __restrict__ C, int M, int Nout) {
  __shared__ u16 sA[128 * 32];  // [m][k]
  __shared__ u16 sB[128 * 32];  // [n][k]
  const int tid = threadIdx.x;
  const int wave = tid >> 6, lane = tid & 63;
  const int m0 = blockIdx.x * 128;
  const int n0 = blockIdx.y * 128;
  const int wm = (wave >> 1) * 64, wn = (wave & 1) * 64;
  const int lrow = lane >> 2, lchunk = lane & 3;  // staging: 16 rows/wave, 4 chunks/row
  const int fr = lane & 15, fq = (lane >> 4) * 8; // fragment row / k-offset

  f32x4 acc[4][4];
#pragma unroll
  for (int i = 0; i < 4; ++i)
#pragma unroll
    for (int j = 0; j < 4; ++j) acc[i][j] = (f32x4){0.f, 0.f, 0.f, 0.f};

  for (int k0 = 0; k0 < 512; k0 += 32) {
#pragma unroll
    for (int pss = 0; pss < 2; ++pss) {
      int rbase = pss * 64 + wave * 16;
      int arow = m0 + rbase + lrow;
      arow = arow < M ? arow : M - 1;           // clamp (extra rows never stored)
      g2lds16(A + (size_t)arow * 512 + k0 + lchunk * 8, &sA[rbase * 32]);
      int brow = n0 + rbase + lrow;
      g2lds16(Bt + (size_t)brow * 512 + k0 + lchunk * 8, &sB[rbase * 32]);
    }
    __builtin_amdgcn_s_waitcnt(0);
    __syncthreads();

    bf16x8 af[4], bfr[4];
#pragma unroll
    for (int t = 0; t < 4; ++t) {
      af[t]  = *reinterpret_cast<const bf16x8*>(&sA[(wm + t * 16 + fr) * 32 + fq]);
      bfr[t] = *reinterpret_cast<const bf16x8*>(&sB[(wn + t * 16 + fr) * 32 + fq]);
    }
#pragma unroll
    for (int i = 0; i < 4; ++i)
#pragma unroll
      for (int j = 0; j < 4; ++j)
        acc[i][j] = __builtin_amdgcn_mfma_f32_16x16x32_bf16(af[i], bfr[j], acc[i][j], 0, 0, 0);
    __syncthreads();
  }

  // C/D layout: col = lane&15, row = (lane>>4)*4 + reg  (m89/m91 verified)
  const int crow0 = m0 + wm + ((lane >> 4) << 2);
  const int ccol0 = n0 + wn + (lane & 15);
#pragma unroll
  for (int i = 0; i < 4; ++i)
#pragma unroll
    for (int j = 0; j < 4; ++j)
#pragma unroll
      for (int r = 0; r < 4; ++r) {
        int row = crow0 + i * 16 + r;
        if (row < M) C[(size_t)row * Nout + ccol0 + j * 16] = f2bf(acc[i][j][r]);
      }
}

// ---------------------------------------------------------------- aggregate
// h[dst] = leaky( sum_{e:dst} dis[src]*dis[dst]*xw[src] + dis[dst]^2*xw[dst] + b )
// One wave per node; lane owns F/64 features; per edge a 64-lane coalesced row gather.
template <int F>
__global__ __launch_bounds__(256)
void agg_kernel(const u16* __restrict__ xw, const int* __restrict__ colv,
                const int* __restrict__ rs, const int* __restrict__ deg,
                const float* __restrict__ dis, const float* __restrict__ bias,
                u16* __restrict__ hout, int N) {
  constexpr int PER = F / 64;
  typedef u16 vec_t __attribute__((ext_vector_type(PER)));
  const int wave = threadIdx.x >> 6;
  const int lane = threadIdx.x & 63;
  const int node = blockIdx.x * 4 + wave;
  if (node >= N) return;
  const int start = rs[node];
  const int end = start + deg[node];
  const float dd = dis[node];
  const int fo = lane * PER;
  float acc[PER];
#pragma unroll
  for (int i = 0; i < PER; ++i) acc[i] = 0.f;

  for (int j = start; j < end; ++j) {
    int s = colv[j];
    float w = dd * dis[s];
    vec_t v = *reinterpret_cast<const vec_t*>(xw + (size_t)s * F + fo);
#pragma unroll
    for (int i = 0; i < PER; ++i) acc[i] += w * bf2f(v[i]);
  }
  {
    float w = dd * dd;  // self loop
    vec_t v = *reinterpret_cast<const vec_t*>(xw + (size_t)node * F + fo);
#pragma unroll
    for (int i = 0; i < PER; ++i) acc[i] += w * bf2f(v[i]);
  }
  vec_t o;
#pragma unroll
  for (int i = 0; i < PER; ++i) {
    float h = acc[i] + bias[fo + i];
    h = h >= 0.f ? h : 0.01f * h;
    o[i] = f2bf(h);
  }
  *reinterpret_cast<vec_t*>(hout + (size_t)node * F + fo) = o;
}

// ---------------------------------------------------------------- pool + FC
__global__ __launch_bounds__(256) void pool_kernel(const u16* __restrict__ h,
                                                   float* __restrict__ pool, int N) {
  int f = threadIdx.x;  // 256 threads, one column each
  float acc = 0.f;
  for (int r = blockIdx.x; r < N; r += gridDim.x)
    acc += bf2f(h[(size_t)r * 256 + f]);
  atomicAdd(&pool[f], acc);
}

__global__ void fc_kernel(const float* __restrict__ pool, const float* __restrict__ fcW1,
                          const float* __restrict__ fcb1, const float* __restrict__ fcW2,
                          const float* __restrict__ fcb2, float* __restrict__ out,
                          float invN) {
  int j = threadIdx.x;  // 64 threads = 1 wave
  float acc = 0.f;
  for (int f = 0; f < 256; ++f) acc += pool[f] * invN * fcW1[f * 64 + j];
  float h = acc + fcb1[j];
  h = h >= 0.f ? h : 0.01f * h;
  float p = h * fcW2[j];
  for (int o = 32; o; o >>= 1) p += __shfl_down(p, o);
  if (j == 0) out[0] = 1.f / (1.f + expf(-(p + fcb2[0])));
}

// ---------------------------------------------------------------- launch
extern "C" void kernel_launch(void* const* d_in, const int* in_sizes, int n_in,
                              void* d_out, int out_size, void* d_ws, size_t ws_size,
                              hipStream_t stream) {
  const float* x    = (const float*)d_in[0];
  const int*   ei   = (const int*)d_in[1];
  const float* W1   = (const float*)d_in[2];
  const float* b1   = (const float*)d_in[3];
  const float* W2   = (const float*)d_in[4];
  const float* b2   = (const float*)d_in[5];
  const float* W3   = (const float*)d_in[6];
  const float* b3   = (const float*)d_in[7];
  const float* W4   = (const float*)d_in[8];
  const float* b4   = (const float*)d_in[9];
  const float* fcW1 = (const float*)d_in[10];
  const float* fcb1 = (const float*)d_in[11];
  const float* fcW2 = (const float*)d_in[12];
  const float* fcb2 = (const float*)d_in[13];
  float* out = (float*)d_out;

  const int N = in_sizes[0] / 512;
  const int E = in_sizes[1] / 2;

  char* p = (char*)d_ws;
  auto carve = [&](size_t bytes) {
    char* r = p;
    p += (bytes + 255) & ~(size_t)255;
    return r;
  };
  u16* bufA = (u16*)carve((size_t)N * 512 * 2);
  u16* bufB = (u16*)carve((size_t)N * 512 * 2);
  u16* bufC = (u16*)carve((size_t)N * 512 * 2);
  u16* Wt1 = (u16*)carve(512 * 512 * 2);
  u16* Wt2 = (u16*)carve(512 * 512 * 2);
  u16* Wt3 = (u16*)carve(512 * 512 * 2);
  u16* Wt4 = (u16*)carve(512 * 256 * 2);
  int* deg    = (int*)carve((size_t)N * 4);
  int* cursor = (int*)carve((size_t)N * 4);
  int* rs     = (int*)carve((size_t)(N + 1) * 4);
  int* colv   = (int*)carve((size_t)E * 4);
  int* bsum   = (int*)carve(1024 * 4);
  int* boff   = (int*)carve(1024 * 4);
  int* flag   = (int*)carve(256);
  float* disv = (float*)carve((size_t)N * 4);
  float* pool = (float*)carve(256 * 4);
  if ((size_t)(p - (char*)d_ws) > ws_size) return;  // need ~318 MB

  const int nb1024 = (N + 1023) / 1024;

  init_kernel<<<(N + 255) / 256, 256, 0, stream>>>(deg, cursor, pool, N);
  detect_kernel<<<1, 256, 0, stream>>>(ei, flag);
  degree_kernel<<<(E + 255) / 256, 256, 0, stream>>>(ei, flag, deg, E);
  dis_kernel<<<(N + 255) / 256, 256, 0, stream>>>(deg, disv, N);
  scan1_kernel<<<nb1024, 1024, 0, stream>>>(deg, rs, bsum, N);
  scan2_kernel<<<1, 64, 0, stream>>>(bsum, boff, nb1024);
  scan3_kernel<<<(N + 255) / 256, 256, 0, stream>>>(rs, boff, N);
  fill_kernel<<<(E + 255) / 256, 256, 0, stream>>>(ei, flag, rs, cursor, colv, E);

  convx_kernel<<<((size_t)N * 512 / 4 + 255) / 256, 256, 0, stream>>>(x, bufA, (size_t)N * 512);
  convw_kernel<<<(512 * 512 + 255) / 256, 256, 0, stream>>>(W1, Wt1, 512);
  convw_kernel<<<(512 * 512 + 255) / 256, 256, 0, stream>>>(W2, Wt2, 512);
  convw_kernel<<<(512 * 512 + 255) / 256, 256, 0, stream>>>(W3, Wt3, 512);
  convw_kernel<<<(512 * 256 + 255) / 256, 256, 0, stream>>>(W4, Wt4, 256);

  const unsigned gm = (unsigned)((N + 127) / 128);
  const unsigned ga = (unsigned)((N + 3) / 4);

  // L1: A -> B(xw) -> C(h1)
  gemm_kernel<<<dim3(gm, 4), 256, 0, stream>>>(bufA, Wt1, bufB, N, 512);
  agg_kernel<512><<<ga, 256, 0, stream>>>(bufB, colv, rs, deg, disv, b1, bufC, N);
  // L2: C -> A(xw) -> B(h2)
  gemm_kernel<<<dim3(gm, 4), 256, 0, stream>>>(bufC, Wt2, bufA, N, 512);
  agg_kernel<512><<<ga, 256, 0, stream>>>(bufA, colv, rs, deg, disv, b2, bufB, N);
  // L3: B -> C(xw) -> A(h3)
  gemm_kernel<<<dim3(gm, 4), 256, 0, stream>>>(bufB, Wt3, bufC, N, 512);
  agg_kernel<512><<<ga, 256, 0, stream>>>(bufC, colv, rs, deg, disv, b3, bufA, N);
  // L4 (256-wide): A -> B(xw4) -> C(h4)
  gemm_kernel<<<dim3(gm, 2), 256, 0, stream>>>(bufA, Wt4, bufB, N, 256);
  agg_kernel<256><<<ga, 256, 0, stream>>>(bufB, colv, rs, deg, disv, b4, bufC, N);

  pool_kernel<<<128, 256, 0, stream>>>(bufC, pool, N);
  fc_kernel<<<1, 64, 0, stream>>>(pool, fcW1, fcb1, fcW2, fcb2, out, 1.0f / (float)N);
}